// Round 2
// baseline (367.108 us; speedup 1.0000x reference)
//
#include <hip/hip_runtime.h>
#include <stdint.h>

#define INP 128
#define OUTD 128
#define WT_STRIDE 136   // k-stride (elements) for W' layout: +8 pad keeps ds_read_b128 16B-aligned
#define THREEFRY_PARTITIONABLE 1  // verified round 1: absmax = one lattice step

typedef __bf16 bf16x8 __attribute__((ext_vector_type(8)));
typedef float  floatx4 __attribute__((ext_vector_type(4)));

// ---------------- threefry2x32 (bit-exact vs jax._src.prng) ----------------
__device__ __forceinline__ uint32_t rotl32(uint32_t v, uint32_t n) {
  return (v << n) | (v >> (32u - n));
}
__device__ __forceinline__ void tf_round(uint32_t& x0, uint32_t& x1, uint32_t r) {
  x0 += x1; x1 = rotl32(x1, r); x1 ^= x0;
}
__device__ void threefry2x32(uint32_t k0, uint32_t k1, uint32_t c0, uint32_t c1,
                             uint32_t& o0, uint32_t& o1) {
  uint32_t k2 = k0 ^ k1 ^ 0x1BD11BDAu;
  uint32_t x0 = c0 + k0, x1 = c1 + k1;
  tf_round(x0,x1,13); tf_round(x0,x1,15); tf_round(x0,x1,26); tf_round(x0,x1,6);
  x0 += k1; x1 += k2 + 1u;
  tf_round(x0,x1,17); tf_round(x0,x1,29); tf_round(x0,x1,16); tf_round(x0,x1,24);
  x0 += k2; x1 += k0 + 2u;
  tf_round(x0,x1,13); tf_round(x0,x1,15); tf_round(x0,x1,26); tf_round(x0,x1,6);
  x0 += k0; x1 += k1 + 3u;
  tf_round(x0,x1,17); tf_round(x0,x1,29); tf_round(x0,x1,16); tf_round(x0,x1,24);
  x0 += k1; x1 += k2 + 4u;
  tf_round(x0,x1,13); tf_round(x0,x1,15); tf_round(x0,x1,26); tf_round(x0,x1,6);
  x0 += k2; x1 += k0 + 5u;
  o0 = x0; o1 = x1;
}

// Giles single-precision erfinv (matches XLA ErfInv32 family; ~1e-6 abs err)
__device__ float erfinv_giles(float x) {
  float w = -logf((1.0f - x) * (1.0f + x));
  float p;
  if (w < 5.0f) {
    w = w - 2.5f;
    p = 2.81022636e-08f;
    p = fmaf(p, w, 3.43273939e-07f);
    p = fmaf(p, w, -3.5233877e-06f);
    p = fmaf(p, w, -4.39150654e-06f);
    p = fmaf(p, w, 0.00021858087f);
    p = fmaf(p, w, -0.00125372503f);
    p = fmaf(p, w, -0.00417768164f);
    p = fmaf(p, w, 0.246640727f);
    p = fmaf(p, w, 1.50140941f);
  } else {
    w = sqrtf(w) - 3.0f;
    p = -0.000200214257f;
    p = fmaf(p, w, 0.000100950558f);
    p = fmaf(p, w, 0.00134934322f);
    p = fmaf(p, w, -0.00367342844f);
    p = fmaf(p, w, 0.00573950773f);
    p = fmaf(p, w, -0.0076224613f);
    p = fmaf(p, w, 0.00943887047f);
    p = fmaf(p, w, 1.00167406f);
    p = fmaf(p, w, 2.83297682f);
  }
  return p * x;
}

__device__ float normal_from_bits(uint32_t bits) {
  const float lo = -0.999999940395355224609375f;
  uint32_t fb = (bits >> 9) | 0x3F800000u;
  float f = __uint_as_float(fb) - 1.0f;
  float u = fmaxf(lo, f * 2.0f + lo);
  return 1.41421356237309515f * erfinv_giles(u);
}

__device__ __forceinline__ uint32_t rand_bits(uint32_t ka, uint32_t kb, int i, int half) {
#if THREEFRY_PARTITIONABLE
  (void)half;
  uint32_t o0, o1;
  threefry2x32(ka, kb, 0u, (uint32_t)i, o0, o1);
  return o0 ^ o1;
#else
  uint32_t c0 = (i < half) ? (uint32_t)i : (uint32_t)(i - half);
  uint32_t o0, o1;
  threefry2x32(ka, kb, c0, c0 + (uint32_t)half, o0, o1);
  return (i < half) ? o0 : o1;
#endif
}

// ---------------- setup A: reductions + bias (1 block, trivial) ----------------
__global__ __launch_bounds__(256) void setup_reduce(
    const float* __restrict__ w, const float* __restrict__ bias,
    float* __restrict__ biasEff, float* __restrict__ scalars) {
  __shared__ float red[8];
  const int tid = threadIdx.x;

  float m = -3.4e38f;
  for (int i = tid; i < INP * OUTD; i += 256) m = fmaxf(m, w[i]);
  #pragma unroll
  for (int off = 1; off < 64; off <<= 1) m = fmaxf(m, __shfl_xor(m, off));
  float bm = (tid < OUTD) ? bias[tid] : -3.4e38f;
  #pragma unroll
  for (int off = 1; off < 64; off <<= 1) bm = fmaxf(bm, __shfl_xor(bm, off));
  if ((tid & 63) == 0) { red[tid >> 6] = m; red[4 + (tid >> 6)] = bm; }
  __syncthreads();
  const float wmax = fmaxf(fmaxf(red[0], red[1]), fmaxf(red[2], red[3]));
  const float bmax = fmaxf(fmaxf(red[4], red[5]), fmaxf(red[6], red[7]));
  if (tid == 0) { scalars[0] = wmax; scalars[1] = bmax; }

  // bias noise (128 elements, cheap enough here)
  uint32_t k2a, k2b;
#if THREEFRY_PARTITIONABLE
  threefry2x32(0u, 1234u, 0u, 1u, k2a, k2b);
#else
  { uint32_t a0, b0, a1, b1;
    threefry2x32(0u, 1234u, 0u, 2u, a0, b0);
    threefry2x32(0u, 1234u, 1u, 3u, a1, b1);
    k2a = b0; k2b = b1; }
#endif
  if (tid < OUTD) {
    float nrm = normal_from_bits(rand_bits(k2a, k2b, tid, OUTD / 2));
    float bv = bias[tid];
    float bq = rintf(fminf(fmaxf(bv * 128.f, -127.f), 127.f)) * 0.0078125f;
    biasEff[tid] = bq + (nrm * bmax) * 0.1f;
  }
}

// ---------------- setup B: weight noise, 64 blocks x 256 (1 elem/thread) ----------------
__global__ __launch_bounds__(256) void setup_noise(
    const float* __restrict__ w, __bf16* __restrict__ wt,
    const float* __restrict__ scalars) {
  const int i = blockIdx.x * 256 + threadIdx.x;   // 0..16383
  const float wmax = scalars[0];

  uint32_t k1a, k1b;
#if THREEFRY_PARTITIONABLE
  threefry2x32(0u, 1234u, 0u, 0u, k1a, k1b);
#else
  { uint32_t a0, b0, a1, b1;
    threefry2x32(0u, 1234u, 0u, 2u, a0, b0);
    threefry2x32(0u, 1234u, 1u, 3u, a1, b1);
    k1a = a0; k1b = a1; }
#endif

  float nrm = normal_from_bits(rand_bits(k1a, k1b, i, (INP * OUTD) / 2));
  int r = i >> 7, c = i & 127;   // w[r][c]: r = k (input dim), c = n (output dim)
  float wv = w[i];
  float wq = rintf(fminf(fmaxf(wv * 128.f, -127.f), 127.f)) * 0.0078125f;
  wt[c * WT_STRIDE + r] = (__bf16)(wq + (nrm * wmax) * 0.1f);
}

// ---------------- main: quant(x) -> MFMA -> quant(out) ----------------
// 512 threads (8 waves) share one 35KB LDS W-tile -> 4 blocks/CU = 32 waves/CU.
// Each wave: 32 rows x 128 cols. Block tile: 256 rows. Grid: 262144/256 = 1024.
__device__ __forceinline__ bf16x8 quant_a(const float* p, float s1, float r1) {
  floatx4 v0 = *(const floatx4*)p;
  floatx4 v1 = *(const floatx4*)(p + 4);
  bf16x8 a;
  #pragma unroll
  for (int i = 0; i < 4; ++i) {
    a[i]     = (__bf16)(rintf(fminf(fmaxf(v0[i] * s1, -127.f), 127.f)) * r1);
    a[i + 4] = (__bf16)(rintf(fminf(fmaxf(v1[i] * s1, -127.f), 127.f)) * r1);
  }
  return a;
}

__global__ __launch_bounds__(512, 8) void linlayer_main(
    const float* __restrict__ x, const __bf16* __restrict__ wt,
    const float* __restrict__ biasEff, const float* __restrict__ a1p,
    const float* __restrict__ a2p, float* __restrict__ out) {
  __shared__ __attribute__((aligned(16))) __bf16 sW[OUTD * WT_STRIDE];
  __shared__ float sBias[OUTD];

  const int tid = threadIdx.x;

  // stage W' (34816 B) into LDS
  {
    const uint4* src = (const uint4*)wt;
    uint4* dst = (uint4*)sW;
    for (int i = tid; i < (OUTD * WT_STRIDE * 2) / 16; i += 512) dst[i] = src[i];
  }
  if (tid < OUTD) sBias[tid] = biasEff[tid];

  const float a1 = a1p[0], a2 = a2p[0];
  const float s1 = 128.0f / a1, r1 = a1 * 0.0078125f;  // 32, 1/32 (exact pow2)
  const float s2 = 128.0f / a2, r2 = a2 * 0.0078125f;  // 8, 0.125

  __syncthreads();

  const int wave = tid >> 6;          // 0..7
  const int lane = tid & 63;
  const int n16  = lane & 15;
  const int quad = lane >> 4;

  const long rowBase = (long)blockIdx.x * 256 + wave * 32;

  floatx4 acc[2][8];
  #pragma unroll
  for (int rt = 0; rt < 2; ++rt)
    #pragma unroll
    for (int ct = 0; ct < 8; ++ct) acc[rt][ct] = (floatx4)0.0f;

  const float* xp0 = x + (size_t)(rowBase + n16) * INP + quad * 8;
  const float* xp1 = xp0 + (size_t)16 * INP;

  #pragma unroll
  for (int kc = 0; kc < 4; ++kc) {
    bf16x8 afrag0 = quant_a(xp0 + kc * 32, s1, r1);
    bf16x8 afrag1 = quant_a(xp1 + kc * 32, s1, r1);
    const int kOff = kc * 32 + quad * 8;
    #pragma unroll
    for (int ct = 0; ct < 8; ++ct) {
      bf16x8 b = *(const bf16x8*)&sW[(ct * 16 + n16) * WT_STRIDE + kOff];
      acc[0][ct] = __builtin_amdgcn_mfma_f32_16x16x32_bf16(afrag0, b, acc[0][ct], 0, 0, 0);
      acc[1][ct] = __builtin_amdgcn_mfma_f32_16x16x32_bf16(afrag1, b, acc[1][ct], 0, 0, 0);
    }
  }

  // epilogue: out = rint(clip(h*8, +/-127)) * 0.125 ; C/D: col=lane&15, row=quad*4+reg
  #pragma unroll
  for (int rt = 0; rt < 2; ++rt) {
    #pragma unroll
    for (int ct = 0; ct < 8; ++ct) {
      const int col = ct * 16 + n16;
      const float bsum = sBias[col];
      #pragma unroll
      for (int r = 0; r < 4; ++r) {
        const long row = rowBase + rt * 16 + quad * 4 + r;
        float h = acc[rt][ct][r] + bsum;
        float t = fminf(fmaxf(h * s2, -127.0f), 127.0f);
        out[(size_t)row * OUTD + col] = rintf(t) * r2;
      }
    }
  }
}

extern "C" void kernel_launch(void* const* d_in, const int* in_sizes, int n_in,
                              void* d_out, int out_size, void* d_ws, size_t ws_size,
                              hipStream_t stream) {
  const float* x    = (const float*)d_in[0];
  const float* w    = (const float*)d_in[1];
  const float* bias = (const float*)d_in[2];
  const float* a1   = (const float*)d_in[3];
  const float* a2   = (const float*)d_in[4];
  float* out = (float*)d_out;

  __bf16* wt     = (__bf16*)d_ws;                                   // 34816 B
  float* biasEff = (float*)((char*)d_ws + OUTD * WT_STRIDE * 2);    // +512 B
  float* scalars = (float*)((char*)d_ws + OUTD * WT_STRIDE * 2 + 512);

  const int rows = in_sizes[0] / INP;     // 262144
  const int grid = rows / 256;            // 1024 blocks, one 256x128 tile each

  setup_reduce<<<1, 256, 0, stream>>>(w, bias, biasEff, scalars);
  setup_noise<<<64, 256, 0, stream>>>(w, wt, scalars);
  linlayer_main<<<grid, 512, 0, stream>>>(x, wt, biasEff, a1, a2, out);
}

// Round 3
// 275.103 us; speedup vs baseline: 1.3344x; 1.3344x over previous
//
#include <hip/hip_runtime.h>
#include <stdint.h>

#define INP 128
#define OUTD 128
#define WT_STRIDE 136   // k-stride (elements) for W' layout: +8 pad keeps ds_read_b128 16B-aligned
#define THREEFRY_PARTITIONABLE 1  // verified round 1: absmax = one lattice step

typedef __bf16 bf16x8 __attribute__((ext_vector_type(8)));
typedef float  floatx4 __attribute__((ext_vector_type(4)));

// ---------------- threefry2x32 (bit-exact vs jax._src.prng) ----------------
__device__ __forceinline__ uint32_t rotl32(uint32_t v, uint32_t n) {
  return (v << n) | (v >> (32u - n));
}
__device__ __forceinline__ void tf_round(uint32_t& x0, uint32_t& x1, uint32_t r) {
  x0 += x1; x1 = rotl32(x1, r); x1 ^= x0;
}
__device__ void threefry2x32(uint32_t k0, uint32_t k1, uint32_t c0, uint32_t c1,
                             uint32_t& o0, uint32_t& o1) {
  uint32_t k2 = k0 ^ k1 ^ 0x1BD11BDAu;
  uint32_t x0 = c0 + k0, x1 = c1 + k1;
  tf_round(x0,x1,13); tf_round(x0,x1,15); tf_round(x0,x1,26); tf_round(x0,x1,6);
  x0 += k1; x1 += k2 + 1u;
  tf_round(x0,x1,17); tf_round(x0,x1,29); tf_round(x0,x1,16); tf_round(x0,x1,24);
  x0 += k2; x1 += k0 + 2u;
  tf_round(x0,x1,13); tf_round(x0,x1,15); tf_round(x0,x1,26); tf_round(x0,x1,6);
  x0 += k0; x1 += k1 + 3u;
  tf_round(x0,x1,17); tf_round(x0,x1,29); tf_round(x0,x1,16); tf_round(x0,x1,24);
  x0 += k1; x1 += k2 + 4u;
  tf_round(x0,x1,13); tf_round(x0,x1,15); tf_round(x0,x1,26); tf_round(x0,x1,6);
  x0 += k2; x1 += k0 + 5u;
  o0 = x0; o1 = x1;
}

// Giles single-precision erfinv (matches XLA ErfInv32 family; ~1e-6 abs err)
__device__ float erfinv_giles(float x) {
  float w = -logf((1.0f - x) * (1.0f + x));
  float p;
  if (w < 5.0f) {
    w = w - 2.5f;
    p = 2.81022636e-08f;
    p = fmaf(p, w, 3.43273939e-07f);
    p = fmaf(p, w, -3.5233877e-06f);
    p = fmaf(p, w, -4.39150654e-06f);
    p = fmaf(p, w, 0.00021858087f);
    p = fmaf(p, w, -0.00125372503f);
    p = fmaf(p, w, -0.00417768164f);
    p = fmaf(p, w, 0.246640727f);
    p = fmaf(p, w, 1.50140941f);
  } else {
    w = sqrtf(w) - 3.0f;
    p = -0.000200214257f;
    p = fmaf(p, w, 0.000100950558f);
    p = fmaf(p, w, 0.00134934322f);
    p = fmaf(p, w, -0.00367342844f);
    p = fmaf(p, w, 0.00573950773f);
    p = fmaf(p, w, -0.0076224613f);
    p = fmaf(p, w, 0.00943887047f);
    p = fmaf(p, w, 1.00167406f);
    p = fmaf(p, w, 2.83297682f);
  }
  return p * x;
}

__device__ float normal_from_bits(uint32_t bits) {
  const float lo = -0.999999940395355224609375f;
  uint32_t fb = (bits >> 9) | 0x3F800000u;
  float f = __uint_as_float(fb) - 1.0f;
  float u = fmaxf(lo, f * 2.0f + lo);
  return 1.41421356237309515f * erfinv_giles(u);
}

__device__ __forceinline__ uint32_t rand_bits(uint32_t ka, uint32_t kb, int i, int half) {
#if THREEFRY_PARTITIONABLE
  (void)half;
  uint32_t o0, o1;
  threefry2x32(ka, kb, 0u, (uint32_t)i, o0, o1);
  return o0 ^ o1;
#else
  uint32_t c0 = (i < half) ? (uint32_t)i : (uint32_t)(i - half);
  uint32_t o0, o1;
  threefry2x32(ka, kb, c0, c0 + (uint32_t)half, o0, o1);
  return (i < half) ? o0 : o1;
#endif
}

// ---------------- setup A: reductions + bias (1 block) ----------------
__global__ __launch_bounds__(256) void setup_reduce(
    const float* __restrict__ w, const float* __restrict__ bias,
    float* __restrict__ biasEff, float* __restrict__ scalars) {
  __shared__ float red[8];
  const int tid = threadIdx.x;

  float m = -3.4e38f;
  for (int i = tid; i < INP * OUTD; i += 256) m = fmaxf(m, w[i]);
  #pragma unroll
  for (int off = 1; off < 64; off <<= 1) m = fmaxf(m, __shfl_xor(m, off));
  float bm = (tid < OUTD) ? bias[tid] : -3.4e38f;
  #pragma unroll
  for (int off = 1; off < 64; off <<= 1) bm = fmaxf(bm, __shfl_xor(bm, off));
  if ((tid & 63) == 0) { red[tid >> 6] = m; red[4 + (tid >> 6)] = bm; }
  __syncthreads();
  const float wmax = fmaxf(fmaxf(red[0], red[1]), fmaxf(red[2], red[3]));
  const float bmax = fmaxf(fmaxf(red[4], red[5]), fmaxf(red[6], red[7]));
  if (tid == 0) { scalars[0] = wmax; scalars[1] = bmax; }

  uint32_t k2a, k2b;
#if THREEFRY_PARTITIONABLE
  threefry2x32(0u, 1234u, 0u, 1u, k2a, k2b);
#else
  { uint32_t a0, b0, a1, b1;
    threefry2x32(0u, 1234u, 0u, 2u, a0, b0);
    threefry2x32(0u, 1234u, 1u, 3u, a1, b1);
    k2a = b0; k2b = b1; }
#endif
  if (tid < OUTD) {
    float nrm = normal_from_bits(rand_bits(k2a, k2b, tid, OUTD / 2));
    float bv = bias[tid];
    float bq = rintf(fminf(fmaxf(bv * 128.f, -127.f), 127.f)) * 0.0078125f;
    biasEff[tid] = bq + (nrm * bmax) * 0.1f;
  }
}

// ---------------- setup B: weight noise, 64 blocks x 256 ----------------
__global__ __launch_bounds__(256) void setup_noise(
    const float* __restrict__ w, __bf16* __restrict__ wt,
    const float* __restrict__ scalars) {
  const int i = blockIdx.x * 256 + threadIdx.x;   // 0..16383
  const float wmax = scalars[0];

  uint32_t k1a, k1b;
#if THREEFRY_PARTITIONABLE
  threefry2x32(0u, 1234u, 0u, 0u, k1a, k1b);
#else
  { uint32_t a0, b0, a1, b1;
    threefry2x32(0u, 1234u, 0u, 2u, a0, b0);
    threefry2x32(0u, 1234u, 1u, 3u, a1, b1);
    k1a = a0; k1b = a1; }
#endif

  float nrm = normal_from_bits(rand_bits(k1a, k1b, i, (INP * OUTD) / 2));
  int r = i >> 7, c = i & 127;   // w[r][c]: r = k (input dim), c = n (output dim)
  float wv = w[i];
  float wq = rintf(fminf(fmaxf(wv * 128.f, -127.f), 127.f)) * 0.0078125f;
  wt[c * WT_STRIDE + r] = (__bf16)(wq + (nrm * wmax) * 0.1f);
}

// ---------------- main ----------------
// Round-1 shape (256 thr, 128-row tile, grid 2048, VGPR 64) with ONE change:
// MFMA operands swapped -> D is transposed -> lane&15 = batch row, reg = out
// col -> epilogue is 16 coalesced global_store_dwordx4 per wave-tile instead
// of 64 scattered dword stores (16x fewer store transactions).
__device__ __forceinline__ bf16x8 quant_a(const float* p, float s1, float r1) {
  floatx4 v0 = *(const floatx4*)p;
  floatx4 v1 = *(const floatx4*)(p + 4);
  bf16x8 a;
  #pragma unroll
  for (int i = 0; i < 4; ++i) {
    a[i]     = (__bf16)(rintf(fminf(fmaxf(v0[i] * s1, -127.f), 127.f)) * r1);
    a[i + 4] = (__bf16)(rintf(fminf(fmaxf(v1[i] * s1, -127.f), 127.f)) * r1);
  }
  return a;
}

__global__ __launch_bounds__(256) void linlayer_main(
    const float* __restrict__ x, const __bf16* __restrict__ wt,
    const float* __restrict__ biasEff, const float* __restrict__ a1p,
    const float* __restrict__ a2p, float* __restrict__ out) {
  __shared__ __attribute__((aligned(16))) __bf16 sW[OUTD * WT_STRIDE];
  __shared__ float sBias[OUTD];

  const int tid = threadIdx.x;

  // stage W' (34816 B) into LDS
  {
    const uint4* src = (const uint4*)wt;
    uint4* dst = (uint4*)sW;
    for (int i = tid; i < (OUTD * WT_STRIDE * 2) / 16; i += 256) dst[i] = src[i];
  }
  if (tid < OUTD) sBias[tid] = biasEff[tid];

  const float a1 = a1p[0], a2 = a2p[0];
  const float s1 = 128.0f / a1, r1 = a1 * 0.0078125f;  // 32, 1/32 (exact pow2)
  const float s2 = 128.0f / a2, r2 = a2 * 0.0078125f;  // 8, 0.125

  __syncthreads();

  const int wave = tid >> 6;
  const int lane = tid & 63;
  const int n16  = lane & 15;
  const int quad = lane >> 4;

  const long rowBase = (long)blockIdx.x * 128 + wave * 32;

  floatx4 acc[2][8];
  #pragma unroll
  for (int rt = 0; rt < 2; ++rt)
    #pragma unroll
    for (int ct = 0; ct < 8; ++ct) acc[rt][ct] = (floatx4)0.0f;

  const float* xp0 = x + (size_t)(rowBase + n16) * INP + quad * 8;
  const float* xp1 = xp0 + (size_t)16 * INP;

  #pragma unroll
  for (int kc = 0; kc < 4; ++kc) {
    bf16x8 afrag0 = quant_a(xp0 + kc * 32, s1, r1);
    bf16x8 afrag1 = quant_a(xp1 + kc * 32, s1, r1);
    const int kOff = kc * 32 + quad * 8;
    #pragma unroll
    for (int ct = 0; ct < 8; ++ct) {
      bf16x8 wfrag = *(const bf16x8*)&sW[(ct * 16 + n16) * WT_STRIDE + kOff];
      // operands swapped vs round 1: D[i=outcol][j=batchrow]
      acc[0][ct] = __builtin_amdgcn_mfma_f32_16x16x32_bf16(wfrag, afrag0, acc[0][ct], 0, 0, 0);
      acc[1][ct] = __builtin_amdgcn_mfma_f32_16x16x32_bf16(wfrag, afrag1, acc[1][ct], 0, 0, 0);
    }
  }

  // epilogue (transposed C/D): lane&15 = batch row within 16-group,
  // quad*4+r = out col within ct-tile -> contiguous floatx4 store per lane.
  #pragma unroll
  for (int rt = 0; rt < 2; ++rt) {
    const size_t row = (size_t)(rowBase + rt * 16 + n16);
    float* orow = out + row * OUTD;
    #pragma unroll
    for (int ct = 0; ct < 8; ++ct) {
      const int colBase = ct * 16 + quad * 4;
      floatx4 v;
      #pragma unroll
      for (int r = 0; r < 4; ++r) {
        float h = acc[rt][ct][r] + sBias[colBase + r];
        float t = fminf(fmaxf(h * s2, -127.0f), 127.0f);
        v[r] = rintf(t) * r2;
      }
      *(floatx4*)(orow + colBase) = v;
    }
  }
}

extern "C" void kernel_launch(void* const* d_in, const int* in_sizes, int n_in,
                              void* d_out, int out_size, void* d_ws, size_t ws_size,
                              hipStream_t stream) {
  const float* x    = (const float*)d_in[0];
  const float* w    = (const float*)d_in[1];
  const float* bias = (const float*)d_in[2];
  const float* a1   = (const float*)d_in[3];
  const float* a2   = (const float*)d_in[4];
  float* out = (float*)d_out;

  __bf16* wt     = (__bf16*)d_ws;                                   // 34816 B
  float* biasEff = (float*)((char*)d_ws + OUTD * WT_STRIDE * 2);    // +512 B
  float* scalars = (float*)((char*)d_ws + OUTD * WT_STRIDE * 2 + 512);

  const int rows = in_sizes[0] / INP;     // 262144
  const int grid = rows / 128;            // 2048 blocks, one 128x128 tile each

  setup_reduce<<<1, 256, 0, stream>>>(w, bias, biasEff, scalars);
  setup_noise<<<64, 256, 0, stream>>>(w, wt, scalars);
  linlayer_main<<<grid, 256, 0, stream>>>(x, wt, biasEff, a1, a2, out);
}

// Round 4
// 272.496 us; speedup vs baseline: 1.3472x; 1.0096x over previous
//
#include <hip/hip_runtime.h>
#include <stdint.h>

#define INP 128
#define OUTD 128
#define WT_STRIDE 136   // k-stride (elements) for W' layout: +8 pad keeps ds_read_b128 16B-aligned
#define THREEFRY_PARTITIONABLE 1  // verified round 1: absmax = one lattice step

typedef __bf16 bf16x8 __attribute__((ext_vector_type(8)));
typedef float  floatx4 __attribute__((ext_vector_type(4)));

// ---------------- threefry2x32 (bit-exact vs jax._src.prng) ----------------
__device__ __forceinline__ uint32_t rotl32(uint32_t v, uint32_t n) {
  return (v << n) | (v >> (32u - n));
}
__device__ __forceinline__ void tf_round(uint32_t& x0, uint32_t& x1, uint32_t r) {
  x0 += x1; x1 = rotl32(x1, r); x1 ^= x0;
}
__device__ void threefry2x32(uint32_t k0, uint32_t k1, uint32_t c0, uint32_t c1,
                             uint32_t& o0, uint32_t& o1) {
  uint32_t k2 = k0 ^ k1 ^ 0x1BD11BDAu;
  uint32_t x0 = c0 + k0, x1 = c1 + k1;
  tf_round(x0,x1,13); tf_round(x0,x1,15); tf_round(x0,x1,26); tf_round(x0,x1,6);
  x0 += k1; x1 += k2 + 1u;
  tf_round(x0,x1,17); tf_round(x0,x1,29); tf_round(x0,x1,16); tf_round(x0,x1,24);
  x0 += k2; x1 += k0 + 2u;
  tf_round(x0,x1,13); tf_round(x0,x1,15); tf_round(x0,x1,26); tf_round(x0,x1,6);
  x0 += k0; x1 += k1 + 3u;
  tf_round(x0,x1,17); tf_round(x0,x1,29); tf_round(x0,x1,16); tf_round(x0,x1,24);
  x0 += k1; x1 += k2 + 4u;
  tf_round(x0,x1,13); tf_round(x0,x1,15); tf_round(x0,x1,26); tf_round(x0,x1,6);
  x0 += k2; x1 += k0 + 5u;
  o0 = x0; o1 = x1;
}

// Giles single-precision erfinv (matches XLA ErfInv32 family; ~1e-6 abs err)
__device__ float erfinv_giles(float x) {
  float w = -logf((1.0f - x) * (1.0f + x));
  float p;
  if (w < 5.0f) {
    w = w - 2.5f;
    p = 2.81022636e-08f;
    p = fmaf(p, w, 3.43273939e-07f);
    p = fmaf(p, w, -3.5233877e-06f);
    p = fmaf(p, w, -4.39150654e-06f);
    p = fmaf(p, w, 0.00021858087f);
    p = fmaf(p, w, -0.00125372503f);
    p = fmaf(p, w, -0.00417768164f);
    p = fmaf(p, w, 0.246640727f);
    p = fmaf(p, w, 1.50140941f);
  } else {
    w = sqrtf(w) - 3.0f;
    p = -0.000200214257f;
    p = fmaf(p, w, 0.000100950558f);
    p = fmaf(p, w, 0.00134934322f);
    p = fmaf(p, w, -0.00367342844f);
    p = fmaf(p, w, 0.00573950773f);
    p = fmaf(p, w, -0.0076224613f);
    p = fmaf(p, w, 0.00943887047f);
    p = fmaf(p, w, 1.00167406f);
    p = fmaf(p, w, 2.83297682f);
  }
  return p * x;
}

__device__ float normal_from_bits(uint32_t bits) {
  const float lo = -0.999999940395355224609375f;
  uint32_t fb = (bits >> 9) | 0x3F800000u;
  float f = __uint_as_float(fb) - 1.0f;
  float u = fmaxf(lo, f * 2.0f + lo);
  return 1.41421356237309515f * erfinv_giles(u);
}

__device__ __forceinline__ uint32_t rand_bits(uint32_t ka, uint32_t kb, int i, int half) {
#if THREEFRY_PARTITIONABLE
  (void)half;
  uint32_t o0, o1;
  threefry2x32(ka, kb, 0u, (uint32_t)i, o0, o1);
  return o0 ^ o1;
#else
  uint32_t c0 = (i < half) ? (uint32_t)i : (uint32_t)(i - half);
  uint32_t o0, o1;
  threefry2x32(ka, kb, c0, c0 + (uint32_t)half, o0, o1);
  return (i < half) ? o0 : o1;
#endif
}

// ---------------- setup A: reductions + bias (1 block) ----------------
__global__ __launch_bounds__(256) void setup_reduce(
    const float* __restrict__ w, const float* __restrict__ bias,
    float* __restrict__ biasEff, float* __restrict__ scalars) {
  __shared__ float red[8];
  const int tid = threadIdx.x;

  float m = -3.4e38f;
  for (int i = tid; i < INP * OUTD; i += 256) m = fmaxf(m, w[i]);
  #pragma unroll
  for (int off = 1; off < 64; off <<= 1) m = fmaxf(m, __shfl_xor(m, off));
  float bm = (tid < OUTD) ? bias[tid] : -3.4e38f;
  #pragma unroll
  for (int off = 1; off < 64; off <<= 1) bm = fmaxf(bm, __shfl_xor(bm, off));
  if ((tid & 63) == 0) { red[tid >> 6] = m; red[4 + (tid >> 6)] = bm; }
  __syncthreads();
  const float wmax = fmaxf(fmaxf(red[0], red[1]), fmaxf(red[2], red[3]));
  const float bmax = fmaxf(fmaxf(red[4], red[5]), fmaxf(red[6], red[7]));
  if (tid == 0) { scalars[0] = wmax; scalars[1] = bmax; }

  uint32_t k2a, k2b;
#if THREEFRY_PARTITIONABLE
  threefry2x32(0u, 1234u, 0u, 1u, k2a, k2b);
#else
  { uint32_t a0, b0, a1, b1;
    threefry2x32(0u, 1234u, 0u, 2u, a0, b0);
    threefry2x32(0u, 1234u, 1u, 3u, a1, b1);
    k2a = b0; k2b = b1; }
#endif
  if (tid < OUTD) {
    float nrm = normal_from_bits(rand_bits(k2a, k2b, tid, OUTD / 2));
    float bv = bias[tid];
    float bq = rintf(fminf(fmaxf(bv * 128.f, -127.f), 127.f)) * 0.0078125f;
    biasEff[tid] = bq + (nrm * bmax) * 0.1f;
  }
}

// ---------------- setup B: weight noise, 64 blocks x 256 ----------------
__global__ __launch_bounds__(256) void setup_noise(
    const float* __restrict__ w, __bf16* __restrict__ wt,
    const float* __restrict__ scalars) {
  const int i = blockIdx.x * 256 + threadIdx.x;   // 0..16383
  const float wmax = scalars[0];

  uint32_t k1a, k1b;
#if THREEFRY_PARTITIONABLE
  threefry2x32(0u, 1234u, 0u, 0u, k1a, k1b);
#else
  { uint32_t a0, b0, a1, b1;
    threefry2x32(0u, 1234u, 0u, 2u, a0, b0);
    threefry2x32(0u, 1234u, 1u, 3u, a1, b1);
    k1a = a0; k1b = a1; }
#endif

  float nrm = normal_from_bits(rand_bits(k1a, k1b, i, (INP * OUTD) / 2));
  int r = i >> 7, c = i & 127;   // w[r][c]: r = k (input dim), c = n (output dim)
  float wv = w[i];
  float wq = rintf(fminf(fmaxf(wv * 128.f, -127.f), 127.f)) * 0.0078125f;
  wt[c * WT_STRIDE + r] = (__bf16)(wq + (nrm * wmax) * 0.1f);
}

// ---------------- main ----------------
// PERSISTENT blocks: grid 1024, each block stages W into LDS once, barriers
// once, then loops over 2 row-tiles with NO further barriers (W is read-only;
// tiles independent). Removes the per-tile stage+barrier latency bubble that
// R1/R3 showed (waves parked, <3 KB/CU in flight).
__device__ __forceinline__ bf16x8 quant_a(const float* p, float s1, float r1) {
  floatx4 v0 = *(const floatx4*)p;
  floatx4 v1 = *(const floatx4*)(p + 4);
  bf16x8 a;
  #pragma unroll
  for (int i = 0; i < 4; ++i) {
    a[i]     = (__bf16)(rintf(fminf(fmaxf(v0[i] * s1, -127.f), 127.f)) * r1);
    a[i + 4] = (__bf16)(rintf(fminf(fmaxf(v1[i] * s1, -127.f), 127.f)) * r1);
  }
  return a;
}

__global__ __launch_bounds__(256) void linlayer_main(
    const float* __restrict__ x, const __bf16* __restrict__ wt,
    const float* __restrict__ biasEff, const float* __restrict__ a1p,
    const float* __restrict__ a2p, float* __restrict__ out, int nTiles) {
  __shared__ __attribute__((aligned(16))) __bf16 sW[OUTD * WT_STRIDE];
  __shared__ float sBias[OUTD];

  const int tid = threadIdx.x;

  // stage W' (34816 B) into LDS — ONCE per block lifetime
  {
    const uint4* src = (const uint4*)wt;
    uint4* dst = (uint4*)sW;
    for (int i = tid; i < (OUTD * WT_STRIDE * 2) / 16; i += 256) dst[i] = src[i];
  }
  if (tid < OUTD) sBias[tid] = biasEff[tid];

  const float a1 = a1p[0], a2 = a2p[0];
  const float s1 = 128.0f / a1, r1 = a1 * 0.0078125f;  // 32, 1/32 (exact pow2)
  const float s2 = 128.0f / a2, r2 = a2 * 0.0078125f;  // 8, 0.125

  __syncthreads();   // the ONLY barrier

  const int wave = tid >> 6;
  const int lane = tid & 63;
  const int n16  = lane & 15;
  const int quad = lane >> 4;

  for (int tile = blockIdx.x; tile < nTiles; tile += gridDim.x) {
    const long rowBase = (long)tile * 128 + wave * 32;

    floatx4 acc[2][8];
    #pragma unroll
    for (int rt = 0; rt < 2; ++rt)
      #pragma unroll
      for (int ct = 0; ct < 8; ++ct) acc[rt][ct] = (floatx4)0.0f;

    const float* xp0 = x + (size_t)(rowBase + n16) * INP + quad * 8;
    const float* xp1 = xp0 + (size_t)16 * INP;

    #pragma unroll
    for (int kc = 0; kc < 4; ++kc) {
      bf16x8 afrag0 = quant_a(xp0 + kc * 32, s1, r1);
      bf16x8 afrag1 = quant_a(xp1 + kc * 32, s1, r1);
      const int kOff = kc * 32 + quad * 8;
      #pragma unroll
      for (int ct = 0; ct < 8; ++ct) {
        bf16x8 wfrag = *(const bf16x8*)&sW[(ct * 16 + n16) * WT_STRIDE + kOff];
        // swapped operands: D[i=outcol][j=batchrow] (transposed C/D)
        acc[0][ct] = __builtin_amdgcn_mfma_f32_16x16x32_bf16(wfrag, afrag0, acc[0][ct], 0, 0, 0);
        acc[1][ct] = __builtin_amdgcn_mfma_f32_16x16x32_bf16(wfrag, afrag1, acc[1][ct], 0, 0, 0);
      }
    }

    // epilogue (transposed C/D): lane&15 = batch row, quad*4+r = out col
    // -> one contiguous floatx4 store per (rt, ct)
    #pragma unroll
    for (int rt = 0; rt < 2; ++rt) {
      const size_t row = (size_t)(rowBase + rt * 16 + n16);
      float* orow = out + row * OUTD;
      #pragma unroll
      for (int ct = 0; ct < 8; ++ct) {
        const int colBase = ct * 16 + quad * 4;
        floatx4 v;
        #pragma unroll
        for (int r = 0; r < 4; ++r) {
          float h = acc[rt][ct][r] + sBias[colBase + r];
          float t = fminf(fmaxf(h * s2, -127.0f), 127.0f);
          v[r] = rintf(t) * r2;
        }
        *(floatx4*)(orow + colBase) = v;
      }
    }
  }
}

extern "C" void kernel_launch(void* const* d_in, const int* in_sizes, int n_in,
                              void* d_out, int out_size, void* d_ws, size_t ws_size,
                              hipStream_t stream) {
  const float* x    = (const float*)d_in[0];
  const float* w    = (const float*)d_in[1];
  const float* bias = (const float*)d_in[2];
  const float* a1   = (const float*)d_in[3];
  const float* a2   = (const float*)d_in[4];
  float* out = (float*)d_out;

  __bf16* wt     = (__bf16*)d_ws;                                   // 34816 B
  float* biasEff = (float*)((char*)d_ws + OUTD * WT_STRIDE * 2);    // +512 B
  float* scalars = (float*)((char*)d_ws + OUTD * WT_STRIDE * 2 + 512);

  const int rows   = in_sizes[0] / INP;   // 262144
  const int nTiles = rows / 128;          // 2048
  const int grid   = 1024;                // 4 blocks/CU (LDS-capped), 2 tiles each

  setup_reduce<<<1, 256, 0, stream>>>(w, bias, biasEff, scalars);
  setup_noise<<<64, 256, 0, stream>>>(w, wt, scalars);
  linlayer_main<<<grid, 256, 0, stream>>>(x, wt, biasEff, a1, a2, out, nTiles);
}

// Round 5
// 271.531 us; speedup vs baseline: 1.3520x; 1.0036x over previous
//
#include <hip/hip_runtime.h>
#include <stdint.h>

#define INP 128
#define OUTD 128
#define WT_STRIDE 136   // k-stride (elements) for W' layout: +8 pad keeps ds_read_b128 16B-aligned
#define THREEFRY_PARTITIONABLE 1  // verified round 1

typedef __bf16 bf16x8 __attribute__((ext_vector_type(8)));
typedef float  floatx4 __attribute__((ext_vector_type(4)));

// ---------------- threefry2x32 (bit-exact vs jax._src.prng) ----------------
__device__ __forceinline__ uint32_t rotl32(uint32_t v, uint32_t n) {
  return (v << n) | (v >> (32u - n));
}
__device__ __forceinline__ void tf_round(uint32_t& x0, uint32_t& x1, uint32_t r) {
  x0 += x1; x1 = rotl32(x1, r); x1 ^= x0;
}
__device__ void threefry2x32(uint32_t k0, uint32_t k1, uint32_t c0, uint32_t c1,
                             uint32_t& o0, uint32_t& o1) {
  uint32_t k2 = k0 ^ k1 ^ 0x1BD11BDAu;
  uint32_t x0 = c0 + k0, x1 = c1 + k1;
  tf_round(x0,x1,13); tf_round(x0,x1,15); tf_round(x0,x1,26); tf_round(x0,x1,6);
  x0 += k1; x1 += k2 + 1u;
  tf_round(x0,x1,17); tf_round(x0,x1,29); tf_round(x0,x1,16); tf_round(x0,x1,24);
  x0 += k2; x1 += k0 + 2u;
  tf_round(x0,x1,13); tf_round(x0,x1,15); tf_round(x0,x1,26); tf_round(x0,x1,6);
  x0 += k0; x1 += k1 + 3u;
  tf_round(x0,x1,17); tf_round(x0,x1,29); tf_round(x0,x1,16); tf_round(x0,x1,24);
  x0 += k1; x1 += k2 + 4u;
  tf_round(x0,x1,13); tf_round(x0,x1,15); tf_round(x0,x1,26); tf_round(x0,x1,6);
  x0 += k2; x1 += k0 + 5u;
  o0 = x0; o1 = x1;
}

// Giles single-precision erfinv (matches XLA ErfInv32 family; ~1e-6 abs err)
__device__ float erfinv_giles(float x) {
  float w = -logf((1.0f - x) * (1.0f + x));
  float p;
  if (w < 5.0f) {
    w = w - 2.5f;
    p = 2.81022636e-08f;
    p = fmaf(p, w, 3.43273939e-07f);
    p = fmaf(p, w, -3.5233877e-06f);
    p = fmaf(p, w, -4.39150654e-06f);
    p = fmaf(p, w, 0.00021858087f);
    p = fmaf(p, w, -0.00125372503f);
    p = fmaf(p, w, -0.00417768164f);
    p = fmaf(p, w, 0.246640727f);
    p = fmaf(p, w, 1.50140941f);
  } else {
    w = sqrtf(w) - 3.0f;
    p = -0.000200214257f;
    p = fmaf(p, w, 0.000100950558f);
    p = fmaf(p, w, 0.00134934322f);
    p = fmaf(p, w, -0.00367342844f);
    p = fmaf(p, w, 0.00573950773f);
    p = fmaf(p, w, -0.0076224613f);
    p = fmaf(p, w, 0.00943887047f);
    p = fmaf(p, w, 1.00167406f);
    p = fmaf(p, w, 2.83297682f);
  }
  return p * x;
}

__device__ float normal_from_bits(uint32_t bits) {
  const float lo = -0.999999940395355224609375f;
  uint32_t fb = (bits >> 9) | 0x3F800000u;
  float f = __uint_as_float(fb) - 1.0f;
  float u = fmaxf(lo, f * 2.0f + lo);
  return 1.41421356237309515f * erfinv_giles(u);
}

__device__ __forceinline__ uint32_t rand_bits(uint32_t ka, uint32_t kb, int i, int half) {
#if THREEFRY_PARTITIONABLE
  (void)half;
  uint32_t o0, o1;
  threefry2x32(ka, kb, 0u, (uint32_t)i, o0, o1);
  return o0 ^ o1;
#else
  uint32_t c0 = (i < half) ? (uint32_t)i : (uint32_t)(i - half);
  uint32_t o0, o1;
  threefry2x32(ka, kb, c0, c0 + (uint32_t)half, o0, o1);
  return (i < half) ? o0 : o1;
#endif
}

// ---------------- setup A: reductions + bias (1 block) ----------------
__global__ __launch_bounds__(256) void setup_reduce(
    const float* __restrict__ w, const float* __restrict__ bias,
    float* __restrict__ biasEff, float* __restrict__ scalars) {
  __shared__ float red[8];
  const int tid = threadIdx.x;

  float m = -3.4e38f;
  for (int i = tid; i < INP * OUTD; i += 256) m = fmaxf(m, w[i]);
  #pragma unroll
  for (int off = 1; off < 64; off <<= 1) m = fmaxf(m, __shfl_xor(m, off));
  float bm = (tid < OUTD) ? bias[tid] : -3.4e38f;
  #pragma unroll
  for (int off = 1; off < 64; off <<= 1) bm = fmaxf(bm, __shfl_xor(bm, off));
  if ((tid & 63) == 0) { red[tid >> 6] = m; red[4 + (tid >> 6)] = bm; }
  __syncthreads();
  const float wmax = fmaxf(fmaxf(red[0], red[1]), fmaxf(red[2], red[3]));
  const float bmax = fmaxf(fmaxf(red[4], red[5]), fmaxf(red[6], red[7]));
  if (tid == 0) { scalars[0] = wmax; scalars[1] = bmax; }

  uint32_t k2a, k2b;
#if THREEFRY_PARTITIONABLE
  threefry2x32(0u, 1234u, 0u, 1u, k2a, k2b);
#else
  { uint32_t a0, b0, a1, b1;
    threefry2x32(0u, 1234u, 0u, 2u, a0, b0);
    threefry2x32(0u, 1234u, 1u, 3u, a1, b1);
    k2a = b0; k2b = b1; }
#endif
  if (tid < OUTD) {
    float nrm = normal_from_bits(rand_bits(k2a, k2b, tid, OUTD / 2));
    float bv = bias[tid];
    float bq = rintf(fminf(fmaxf(bv * 128.f, -127.f), 127.f)) * 0.0078125f;
    biasEff[tid] = bq + (nrm * bmax) * 0.1f;
  }
}

// ---------------- setup B: weight noise, 64 blocks x 256 ----------------
__global__ __launch_bounds__(256) void setup_noise(
    const float* __restrict__ w, __bf16* __restrict__ wt,
    const float* __restrict__ scalars) {
  const int i = blockIdx.x * 256 + threadIdx.x;   // 0..16383
  const float wmax = scalars[0];

  uint32_t k1a, k1b;
#if THREEFRY_PARTITIONABLE
  threefry2x32(0u, 1234u, 0u, 0u, k1a, k1b);
#else
  { uint32_t a0, b0, a1, b1;
    threefry2x32(0u, 1234u, 0u, 2u, a0, b0);
    threefry2x32(0u, 1234u, 1u, 3u, a1, b1);
    k1a = a0; k1b = a1; }
#endif

  float nrm = normal_from_bits(rand_bits(k1a, k1b, i, (INP * OUTD) / 2));
  int r = i >> 7, c = i & 127;   // w[r][c]: r = k (input dim), c = n (output dim)
  float wv = w[i];
  float wq = rintf(fminf(fmaxf(wv * 128.f, -127.f), 127.f)) * 0.0078125f;
  wt[c * WT_STRIDE + r] = (__bf16)(wq + (nrm * wmax) * 0.1f);
}

// ---------------- main ----------------
// R5 "deep stream": 16-row wave-tiles, register double-buffer across tiles so
// every wave ALWAYS has the next tile's 8 KB of loads in flight (R1-R4 were
// phase-locked: loads drained, then a memory-silent compute phase -> ~3 KB/CU
// in flight -> 2.2 TB/s). Grid 1024 persistent, exactly 4 tiles/wave.
__device__ __forceinline__ void load_tile(floatx4 v[8], const float* __restrict__ x,
                                          long tile, int n16, int quad) {
  const float* p = x + ((size_t)(tile * 16 + n16) << 7) + quad * 8;
  #pragma unroll
  for (int kc = 0; kc < 4; ++kc) {
    v[2 * kc]     = *(const floatx4*)(p + kc * 32);
    v[2 * kc + 1] = *(const floatx4*)(p + kc * 32 + 4);
  }
}

__device__ __forceinline__ bf16x8 quant_pair(floatx4 v0, floatx4 v1, float s1, float r1) {
  bf16x8 a;
  #pragma unroll
  for (int i = 0; i < 4; ++i) {
    a[i]     = (__bf16)(rintf(fminf(fmaxf(v0[i] * s1, -127.f), 127.f)) * r1);
    a[i + 4] = (__bf16)(rintf(fminf(fmaxf(v1[i] * s1, -127.f), 127.f)) * r1);
  }
  return a;
}

__device__ __forceinline__ void compute_tile(
    const floatx4 v[8], const __bf16* sW, const float* sBias,
    float* __restrict__ out, long tile, int n16, int quad,
    float s1, float r1, float s2, float r2) {
  floatx4 acc[8];
  #pragma unroll
  for (int ct = 0; ct < 8; ++ct) acc[ct] = (floatx4)0.0f;

  #pragma unroll
  for (int kc = 0; kc < 4; ++kc) {
    bf16x8 a = quant_pair(v[2 * kc], v[2 * kc + 1], s1, r1);
    const int kOff = kc * 32 + quad * 8;
    #pragma unroll
    for (int ct = 0; ct < 8; ++ct) {
      bf16x8 wfrag = *(const bf16x8*)&sW[(ct * 16 + n16) * WT_STRIDE + kOff];
      // swapped operands: D[i=outcol][j=batchrow] (transposed C/D)
      acc[ct] = __builtin_amdgcn_mfma_f32_16x16x32_bf16(wfrag, a, acc[ct], 0, 0, 0);
    }
  }

  float* orow = out + ((size_t)(tile * 16 + n16) << 7);
  #pragma unroll
  for (int ct = 0; ct < 8; ++ct) {
    const int colBase = ct * 16 + quad * 4;
    floatx4 o;
    #pragma unroll
    for (int r = 0; r < 4; ++r) {
      float h = acc[ct][r] + sBias[colBase + r];
      float t = fminf(fmaxf(h * s2, -127.0f), 127.0f);
      o[r] = rintf(t) * r2;
    }
    *(floatx4*)(orow + colBase) = o;
  }
}

__global__ __launch_bounds__(256) void linlayer_main(
    const float* __restrict__ x, const __bf16* __restrict__ wt,
    const float* __restrict__ biasEff, const float* __restrict__ a1p,
    const float* __restrict__ a2p, float* __restrict__ out, int nTiles) {
  __shared__ __attribute__((aligned(16))) __bf16 sW[OUTD * WT_STRIDE];
  __shared__ float sBias[OUTD];

  const int tid  = threadIdx.x;
  const int lane = tid & 63;
  const int n16  = lane & 15;
  const int quad = lane >> 4;

  const int nWaves = gridDim.x * 4;
  const int waveId = blockIdx.x * 4 + (tid >> 6);
  const long last  = nTiles - 1;

  // prefetch tile 0 BEFORE the W-stage barrier (registers only, no LDS dep)
  floatx4 bufA[8], bufB[8];
  long t = waveId;
  load_tile(bufA, x, (t <= last) ? t : last, n16, quad);

  // stage W' (34816 B) into LDS — once per block
  {
    const uint4* src = (const uint4*)wt;
    uint4* dst = (uint4*)sW;
    for (int i = tid; i < (OUTD * WT_STRIDE * 2) / 16; i += 256) dst[i] = src[i];
  }
  if (tid < OUTD) sBias[tid] = biasEff[tid];

  const float a1 = a1p[0], a2 = a2p[0];
  const float s1 = 128.0f / a1, r1 = a1 * 0.0078125f;  // 32, 1/32 (exact pow2)
  const float s2 = 128.0f / a2, r2 = a2 * 0.0078125f;  // 8, 0.125

  __syncthreads();   // the only barrier

  while (t <= last) {
    long tn = t + nWaves;
    load_tile(bufB, x, (tn <= last) ? tn : last, n16, quad);   // in flight during compute(bufA)
    compute_tile(bufA, sW, sBias, out, t, n16, quad, s1, r1, s2, r2);
    t = tn;
    if (t > last) break;

    tn = t + nWaves;
    load_tile(bufA, x, (tn <= last) ? tn : last, n16, quad);   // in flight during compute(bufB)
    compute_tile(bufB, sW, sBias, out, t, n16, quad, s1, r1, s2, r2);
    t = tn;
  }
}

extern "C" void kernel_launch(void* const* d_in, const int* in_sizes, int n_in,
                              void* d_out, int out_size, void* d_ws, size_t ws_size,
                              hipStream_t stream) {
  const float* x    = (const float*)d_in[0];
  const float* w    = (const float*)d_in[1];
  const float* bias = (const float*)d_in[2];
  const float* a1   = (const float*)d_in[3];
  const float* a2   = (const float*)d_in[4];
  float* out = (float*)d_out;

  __bf16* wt     = (__bf16*)d_ws;                                   // 34816 B
  float* biasEff = (float*)((char*)d_ws + OUTD * WT_STRIDE * 2);    // +512 B
  float* scalars = (float*)((char*)d_ws + OUTD * WT_STRIDE * 2 + 512);

  const int rows   = in_sizes[0] / INP;   // 262144
  const int nTiles = rows / 16;           // 16384 16-row wave-tiles
  const int grid   = 1024;                // 4096 waves -> exactly 4 tiles/wave

  setup_reduce<<<1, 256, 0, stream>>>(w, bias, biasEff, scalars);
  setup_noise<<<64, 256, 0, stream>>>(w, wt, scalars);
  linlayer_main<<<grid, 256, 0, stream>>>(x, wt, biasEff, a1, a2, out, nTiles);
}

// Round 6
// 265.466 us; speedup vs baseline: 1.3829x; 1.0228x over previous
//
#include <hip/hip_runtime.h>
#include <stdint.h>

#define INP 128
#define OUTD 128
#define WT_STRIDE 136   // k-stride (elements) for W' layout: +8 pad keeps ds_read_b128 16B-aligned
#define THREEFRY_PARTITIONABLE 1  // verified round 1

typedef __bf16 bf16x8 __attribute__((ext_vector_type(8)));
typedef float  floatx4 __attribute__((ext_vector_type(4)));

// ---------------- threefry2x32 (bit-exact vs jax._src.prng) ----------------
__device__ __forceinline__ uint32_t rotl32(uint32_t v, uint32_t n) {
  return (v << n) | (v >> (32u - n));
}
__device__ __forceinline__ void tf_round(uint32_t& x0, uint32_t& x1, uint32_t r) {
  x0 += x1; x1 = rotl32(x1, r); x1 ^= x0;
}
__device__ void threefry2x32(uint32_t k0, uint32_t k1, uint32_t c0, uint32_t c1,
                             uint32_t& o0, uint32_t& o1) {
  uint32_t k2 = k0 ^ k1 ^ 0x1BD11BDAu;
  uint32_t x0 = c0 + k0, x1 = c1 + k1;
  tf_round(x0,x1,13); tf_round(x0,x1,15); tf_round(x0,x1,26); tf_round(x0,x1,6);
  x0 += k1; x1 += k2 + 1u;
  tf_round(x0,x1,17); tf_round(x0,x1,29); tf_round(x0,x1,16); tf_round(x0,x1,24);
  x0 += k2; x1 += k0 + 2u;
  tf_round(x0,x1,13); tf_round(x0,x1,15); tf_round(x0,x1,26); tf_round(x0,x1,6);
  x0 += k0; x1 += k1 + 3u;
  tf_round(x0,x1,17); tf_round(x0,x1,29); tf_round(x0,x1,16); tf_round(x0,x1,24);
  x0 += k1; x1 += k2 + 4u;
  tf_round(x0,x1,13); tf_round(x0,x1,15); tf_round(x0,x1,26); tf_round(x0,x1,6);
  x0 += k2; x1 += k0 + 5u;
  o0 = x0; o1 = x1;
}

// Giles single-precision erfinv (matches XLA ErfInv32 family; ~1e-6 abs err)
__device__ float erfinv_giles(float x) {
  float w = -logf((1.0f - x) * (1.0f + x));
  float p;
  if (w < 5.0f) {
    w = w - 2.5f;
    p = 2.81022636e-08f;
    p = fmaf(p, w, 3.43273939e-07f);
    p = fmaf(p, w, -3.5233877e-06f);
    p = fmaf(p, w, -4.39150654e-06f);
    p = fmaf(p, w, 0.00021858087f);
    p = fmaf(p, w, -0.00125372503f);
    p = fmaf(p, w, -0.00417768164f);
    p = fmaf(p, w, 0.246640727f);
    p = fmaf(p, w, 1.50140941f);
  } else {
    w = sqrtf(w) - 3.0f;
    p = -0.000200214257f;
    p = fmaf(p, w, 0.000100950558f);
    p = fmaf(p, w, 0.00134934322f);
    p = fmaf(p, w, -0.00367342844f);
    p = fmaf(p, w, 0.00573950773f);
    p = fmaf(p, w, -0.0076224613f);
    p = fmaf(p, w, 0.00943887047f);
    p = fmaf(p, w, 1.00167406f);
    p = fmaf(p, w, 2.83297682f);
  }
  return p * x;
}

__device__ float normal_from_bits(uint32_t bits) {
  const float lo = -0.999999940395355224609375f;
  uint32_t fb = (bits >> 9) | 0x3F800000u;
  float f = __uint_as_float(fb) - 1.0f;
  float u = fmaxf(lo, f * 2.0f + lo);
  return 1.41421356237309515f * erfinv_giles(u);
}

__device__ __forceinline__ uint32_t rand_bits(uint32_t ka, uint32_t kb, int i, int half) {
#if THREEFRY_PARTITIONABLE
  (void)half;
  uint32_t o0, o1;
  threefry2x32(ka, kb, 0u, (uint32_t)i, o0, o1);
  return o0 ^ o1;
#else
  uint32_t c0 = (i < half) ? (uint32_t)i : (uint32_t)(i - half);
  uint32_t o0, o1;
  threefry2x32(ka, kb, c0, c0 + (uint32_t)half, o0, o1);
  return (i < half) ? o0 : o1;
#endif
}

// ---------------- setup A: reductions + bias (1 block) ----------------
__global__ __launch_bounds__(256) void setup_reduce(
    const float* __restrict__ w, const float* __restrict__ bias,
    float* __restrict__ biasEff, float* __restrict__ scalars) {
  __shared__ float red[8];
  const int tid = threadIdx.x;

  float m = -3.4e38f;
  for (int i = tid; i < INP * OUTD; i += 256) m = fmaxf(m, w[i]);
  #pragma unroll
  for (int off = 1; off < 64; off <<= 1) m = fmaxf(m, __shfl_xor(m, off));
  float bm = (tid < OUTD) ? bias[tid] : -3.4e38f;
  #pragma unroll
  for (int off = 1; off < 64; off <<= 1) bm = fmaxf(bm, __shfl_xor(bm, off));
  if ((tid & 63) == 0) { red[tid >> 6] = m; red[4 + (tid >> 6)] = bm; }
  __syncthreads();
  const float wmax = fmaxf(fmaxf(red[0], red[1]), fmaxf(red[2], red[3]));
  const float bmax = fmaxf(fmaxf(red[4], red[5]), fmaxf(red[6], red[7]));
  if (tid == 0) { scalars[0] = wmax; scalars[1] = bmax; }

  uint32_t k2a, k2b;
#if THREEFRY_PARTITIONABLE
  threefry2x32(0u, 1234u, 0u, 1u, k2a, k2b);
#else
  { uint32_t a0, b0, a1, b1;
    threefry2x32(0u, 1234u, 0u, 2u, a0, b0);
    threefry2x32(0u, 1234u, 1u, 3u, a1, b1);
    k2a = b0; k2b = b1; }
#endif
  if (tid < OUTD) {
    float nrm = normal_from_bits(rand_bits(k2a, k2b, tid, OUTD / 2));
    float bv = bias[tid];
    float bq = rintf(fminf(fmaxf(bv * 128.f, -127.f), 127.f)) * 0.0078125f;
    biasEff[tid] = bq + (nrm * bmax) * 0.1f;
  }
}

// ---------------- setup B: weight noise, 64 blocks x 256 ----------------
__global__ __launch_bounds__(256) void setup_noise(
    const float* __restrict__ w, __bf16* __restrict__ wt,
    const float* __restrict__ scalars) {
  const int i = blockIdx.x * 256 + threadIdx.x;   // 0..16383
  const float wmax = scalars[0];

  uint32_t k1a, k1b;
#if THREEFRY_PARTITIONABLE
  threefry2x32(0u, 1234u, 0u, 0u, k1a, k1b);
#else
  { uint32_t a0, b0, a1, b1;
    threefry2x32(0u, 1234u, 0u, 2u, a0, b0);
    threefry2x32(0u, 1234u, 1u, 3u, a1, b1);
    k1a = a0; k1b = a1; }
#endif

  float nrm = normal_from_bits(rand_bits(k1a, k1b, i, (INP * OUTD) / 2));
  int r = i >> 7, c = i & 127;   // w[r][c]: r = k (input dim), c = n (output dim)
  float wv = w[i];
  float wq = rintf(fminf(fmaxf(wv * 128.f, -127.f), 127.f)) * 0.0078125f;
  wt[c * WT_STRIDE + r] = (__bf16)(wq + (nrm * wmax) * 0.1f);
}

// ---------------- main ----------------
// R6: R5 deep-stream structure + FULL-LINE NONTEMPORAL STORES. Epilogue
// round-trips the 16x128 wave-tile through per-wave LDS (stride 132) so each
// global store is 1 KB contiguous (8 full 128-B TCC lines per instruction)
// and nontemporal (no L2/L3 allocation -> no pollution, no half-line merge).
// No block barrier in the loop; only a per-wave s_waitcnt lgkmcnt(0).
#define E_STRIDE 132   // floats; 132*4B: n16*528 -> bank 4*n16, 2-way max (free)

__device__ __forceinline__ void load_tile(floatx4 v[8], const float* __restrict__ x,
                                          long tile, int n16, int quad) {
  const float* p = x + ((size_t)(tile * 16 + n16) << 7) + quad * 8;
  #pragma unroll
  for (int kc = 0; kc < 4; ++kc) {
    v[2 * kc]     = *(const floatx4*)(p + kc * 32);
    v[2 * kc + 1] = *(const floatx4*)(p + kc * 32 + 4);
  }
}

__device__ __forceinline__ bf16x8 quant_pair(floatx4 v0, floatx4 v1, float s1, float r1) {
  bf16x8 a;
  #pragma unroll
  for (int i = 0; i < 4; ++i) {
    a[i]     = (__bf16)(rintf(fminf(fmaxf(v0[i] * s1, -127.f), 127.f)) * r1);
    a[i + 4] = (__bf16)(rintf(fminf(fmaxf(v1[i] * s1, -127.f), 127.f)) * r1);
  }
  return a;
}

__device__ __forceinline__ void compute_tile(
    const floatx4 v[8], const __bf16* sW, const float* sBias, float* myE,
    float* __restrict__ out, long tile, int lane, int n16, int quad,
    float s1, float r1, float s2, float r2) {
  floatx4 acc[8];
  #pragma unroll
  for (int ct = 0; ct < 8; ++ct) acc[ct] = (floatx4)0.0f;

  #pragma unroll
  for (int kc = 0; kc < 4; ++kc) {
    bf16x8 a = quant_pair(v[2 * kc], v[2 * kc + 1], s1, r1);
    const int kOff = kc * 32 + quad * 8;
    #pragma unroll
    for (int ct = 0; ct < 8; ++ct) {
      bf16x8 wfrag = *(const bf16x8*)&sW[(ct * 16 + n16) * WT_STRIDE + kOff];
      // swapped operands: D[i=outcol][j=batchrow] (transposed C/D)
      acc[ct] = __builtin_amdgcn_mfma_f32_16x16x32_bf16(wfrag, a, acc[ct], 0, 0, 0);
    }
  }

  // quantize + deposit into per-wave LDS tile (row = n16, col = ct*16+quad*4)
  #pragma unroll
  for (int ct = 0; ct < 8; ++ct) {
    const int colBase = ct * 16 + quad * 4;
    floatx4 o;
    #pragma unroll
    for (int r = 0; r < 4; ++r) {
      float h = acc[ct][r] + sBias[colBase + r];
      float t = fminf(fmaxf(h * s2, -127.0f), 127.0f);
      o[r] = rintf(t) * r2;
    }
    *(floatx4*)&myE[n16 * E_STRIDE + colBase] = o;
  }

  // drain LDS writes only (lgkm), NOT the global prefetch queue (vmcnt)
  asm volatile("s_waitcnt lgkmcnt(0)" ::: "memory");

  // read back row-linear; store 1KB-contiguous, nontemporal (full 128B lines)
  float* outBase = out + ((size_t)tile << 11);   // tile * 16 rows * 128 cols
  #pragma unroll
  for (int k = 0; k < 8; ++k) {
    const int fl  = k * 256 + lane * 4;          // float offset in 16x128 tile
    const int row = fl >> 7, col = fl & 127;
    floatx4 t = *(const floatx4*)&myE[row * E_STRIDE + col];
    __builtin_nontemporal_store(t, (floatx4*)(outBase + fl));
  }
}

__global__ __launch_bounds__(256) void linlayer_main(
    const float* __restrict__ x, const __bf16* __restrict__ wt,
    const float* __restrict__ biasEff, const float* __restrict__ a1p,
    const float* __restrict__ a2p, float* __restrict__ out, int nTiles) {
  __shared__ __attribute__((aligned(16))) __bf16 sW[OUTD * WT_STRIDE];
  __shared__ __attribute__((aligned(16))) float sE[4][16 * E_STRIDE];
  __shared__ float sBias[OUTD];

  const int tid  = threadIdx.x;
  const int wave = tid >> 6;
  const int lane = tid & 63;
  const int n16  = lane & 15;
  const int quad = lane >> 4;

  const int nWaves = gridDim.x * 4;
  const int waveId = blockIdx.x * 4 + wave;
  const long last  = nTiles - 1;

  // prefetch tile 0 BEFORE the W-stage barrier (registers only, no LDS dep)
  floatx4 bufA[8], bufB[8];
  long t = waveId;
  load_tile(bufA, x, (t <= last) ? t : last, n16, quad);

  // stage W' (34816 B) into LDS — once per block
  {
    const uint4* src = (const uint4*)wt;
    uint4* dst = (uint4*)sW;
    for (int i = tid; i < (OUTD * WT_STRIDE * 2) / 16; i += 256) dst[i] = src[i];
  }
  if (tid < OUTD) sBias[tid] = biasEff[tid];

  const float a1 = a1p[0], a2 = a2p[0];
  const float s1 = 128.0f / a1, r1 = a1 * 0.0078125f;  // 32, 1/32 (exact pow2)
  const float s2 = 128.0f / a2, r2 = a2 * 0.0078125f;  // 8, 0.125

  __syncthreads();   // the only barrier

  float* myE = sE[wave];

  while (t <= last) {
    long tn = t + nWaves;
    load_tile(bufB, x, (tn <= last) ? tn : last, n16, quad);   // in flight during compute(bufA)
    compute_tile(bufA, sW, sBias, myE, out, t, lane, n16, quad, s1, r1, s2, r2);
    t = tn;
    if (t > last) break;

    tn = t + nWaves;
    load_tile(bufA, x, (tn <= last) ? tn : last, n16, quad);   // in flight during compute(bufB)
    compute_tile(bufB, sW, sBias, myE, out, t, lane, n16, quad, s1, r1, s2, r2);
    t = tn;
  }
}

extern "C" void kernel_launch(void* const* d_in, const int* in_sizes, int n_in,
                              void* d_out, int out_size, void* d_ws, size_t ws_size,
                              hipStream_t stream) {
  const float* x    = (const float*)d_in[0];
  const float* w    = (const float*)d_in[1];
  const float* bias = (const float*)d_in[2];
  const float* a1   = (const float*)d_in[3];
  const float* a2   = (const float*)d_in[4];
  float* out = (float*)d_out;

  __bf16* wt     = (__bf16*)d_ws;                                   // 34816 B
  float* biasEff = (float*)((char*)d_ws + OUTD * WT_STRIDE * 2);    // +512 B
  float* scalars = (float*)((char*)d_ws + OUTD * WT_STRIDE * 2 + 512);

  const int rows   = in_sizes[0] / INP;   // 262144
  const int nTiles = rows / 16;           // 16384 16-row wave-tiles
  const int grid   = 512;                 // ~70KB LDS -> 2 blocks/CU resident

  setup_reduce<<<1, 256, 0, stream>>>(w, bias, biasEff, scalars);
  setup_noise<<<64, 256, 0, stream>>>(w, wt, scalars);
  linlayer_main<<<grid, 256, 0, stream>>>(x, wt, biasEff, a1, a2, out, nTiles);
}

// Round 7
// 264.567 us; speedup vs baseline: 1.3876x; 1.0034x over previous
//
#include <hip/hip_runtime.h>
#include <stdint.h>

#define INP 128
#define OUTD 128
#define WT_STRIDE 136   // k-stride (elements) for W' layout: +8 pad keeps ds_read_b128 16B-aligned
#define XT_STRIDE 132   // floats per row of the per-wave LDS x-tile: 132%8=4 -> row term spreads banks
#define THREEFRY_PARTITIONABLE 1  // verified round 1

typedef __bf16 bf16x8 __attribute__((ext_vector_type(8)));
typedef float  floatx4 __attribute__((ext_vector_type(4)));

// ---------------- threefry2x32 (bit-exact vs jax._src.prng) ----------------
__device__ __forceinline__ uint32_t rotl32(uint32_t v, uint32_t n) {
  return (v << n) | (v >> (32u - n));
}
__device__ __forceinline__ void tf_round(uint32_t& x0, uint32_t& x1, uint32_t r) {
  x0 += x1; x1 = rotl32(x1, r); x1 ^= x0;
}
__device__ void threefry2x32(uint32_t k0, uint32_t k1, uint32_t c0, uint32_t c1,
                             uint32_t& o0, uint32_t& o1) {
  uint32_t k2 = k0 ^ k1 ^ 0x1BD11BDAu;
  uint32_t x0 = c0 + k0, x1 = c1 + k1;
  tf_round(x0,x1,13); tf_round(x0,x1,15); tf_round(x0,x1,26); tf_round(x0,x1,6);
  x0 += k1; x1 += k2 + 1u;
  tf_round(x0,x1,17); tf_round(x0,x1,29); tf_round(x0,x1,16); tf_round(x0,x1,24);
  x0 += k2; x1 += k0 + 2u;
  tf_round(x0,x1,13); tf_round(x0,x1,15); tf_round(x0,x1,26); tf_round(x0,x1,6);
  x0 += k0; x1 += k1 + 3u;
  tf_round(x0,x1,17); tf_round(x0,x1,29); tf_round(x0,x1,16); tf_round(x0,x1,24);
  x0 += k1; x1 += k2 + 4u;
  tf_round(x0,x1,13); tf_round(x0,x1,15); tf_round(x0,x1,26); tf_round(x0,x1,6);
  x0 += k2; x1 += k0 + 5u;
  o0 = x0; o1 = x1;
}

// Giles single-precision erfinv (matches XLA ErfInv32 family; ~1e-6 abs err)
__device__ float erfinv_giles(float x) {
  float w = -logf((1.0f - x) * (1.0f + x));
  float p;
  if (w < 5.0f) {
    w = w - 2.5f;
    p = 2.81022636e-08f;
    p = fmaf(p, w, 3.43273939e-07f);
    p = fmaf(p, w, -3.5233877e-06f);
    p = fmaf(p, w, -4.39150654e-06f);
    p = fmaf(p, w, 0.00021858087f);
    p = fmaf(p, w, -0.00125372503f);
    p = fmaf(p, w, -0.00417768164f);
    p = fmaf(p, w, 0.246640727f);
    p = fmaf(p, w, 1.50140941f);
  } else {
    w = sqrtf(w) - 3.0f;
    p = -0.000200214257f;
    p = fmaf(p, w, 0.000100950558f);
    p = fmaf(p, w, 0.00134934322f);
    p = fmaf(p, w, -0.00367342844f);
    p = fmaf(p, w, 0.00573950773f);
    p = fmaf(p, w, -0.0076224613f);
    p = fmaf(p, w, 0.00943887047f);
    p = fmaf(p, w, 1.00167406f);
    p = fmaf(p, w, 2.83297682f);
  }
  return p * x;
}

__device__ float normal_from_bits(uint32_t bits) {
  const float lo = -0.999999940395355224609375f;
  uint32_t fb = (bits >> 9) | 0x3F800000u;
  float f = __uint_as_float(fb) - 1.0f;
  float u = fmaxf(lo, f * 2.0f + lo);
  return 1.41421356237309515f * erfinv_giles(u);
}

__device__ __forceinline__ uint32_t rand_bits(uint32_t ka, uint32_t kb, int i, int half) {
#if THREEFRY_PARTITIONABLE
  (void)half;
  uint32_t o0, o1;
  threefry2x32(ka, kb, 0u, (uint32_t)i, o0, o1);
  return o0 ^ o1;
#else
  uint32_t c0 = (i < half) ? (uint32_t)i : (uint32_t)(i - half);
  uint32_t o0, o1;
  threefry2x32(ka, kb, c0, c0 + (uint32_t)half, o0, o1);
  return (i < half) ? o0 : o1;
#endif
}

// ---------------- setup A: reductions + bias (1 block) ----------------
__global__ __launch_bounds__(256) void setup_reduce(
    const float* __restrict__ w, const float* __restrict__ bias,
    float* __restrict__ biasEff, float* __restrict__ scalars) {
  __shared__ float red[8];
  const int tid = threadIdx.x;

  float m = -3.4e38f;
  for (int i = tid; i < INP * OUTD; i += 256) m = fmaxf(m, w[i]);
  #pragma unroll
  for (int off = 1; off < 64; off <<= 1) m = fmaxf(m, __shfl_xor(m, off));
  float bm = (tid < OUTD) ? bias[tid] : -3.4e38f;
  #pragma unroll
  for (int off = 1; off < 64; off <<= 1) bm = fmaxf(bm, __shfl_xor(bm, off));
  if ((tid & 63) == 0) { red[tid >> 6] = m; red[4 + (tid >> 6)] = bm; }
  __syncthreads();
  const float wmax = fmaxf(fmaxf(red[0], red[1]), fmaxf(red[2], red[3]));
  const float bmax = fmaxf(fmaxf(red[4], red[5]), fmaxf(red[6], red[7]));
  if (tid == 0) { scalars[0] = wmax; scalars[1] = bmax; }

  uint32_t k2a, k2b;
#if THREEFRY_PARTITIONABLE
  threefry2x32(0u, 1234u, 0u, 1u, k2a, k2b);
#else
  { uint32_t a0, b0, a1, b1;
    threefry2x32(0u, 1234u, 0u, 2u, a0, b0);
    threefry2x32(0u, 1234u, 1u, 3u, a1, b1);
    k2a = b0; k2b = b1; }
#endif
  if (tid < OUTD) {
    float nrm = normal_from_bits(rand_bits(k2a, k2b, tid, OUTD / 2));
    float bv = bias[tid];
    float bq = rintf(fminf(fmaxf(bv * 128.f, -127.f), 127.f)) * 0.0078125f;
    biasEff[tid] = bq + (nrm * bmax) * 0.1f;
  }
}

// ---------------- setup B: weight noise, 64 blocks x 256 ----------------
__global__ __launch_bounds__(256) void setup_noise(
    const float* __restrict__ w, __bf16* __restrict__ wt,
    const float* __restrict__ scalars) {
  const int i = blockIdx.x * 256 + threadIdx.x;   // 0..16383
  const float wmax = scalars[0];

  uint32_t k1a, k1b;
#if THREEFRY_PARTITIONABLE
  threefry2x32(0u, 1234u, 0u, 0u, k1a, k1b);
#else
  { uint32_t a0, b0, a1, b1;
    threefry2x32(0u, 1234u, 0u, 2u, a0, b0);
    threefry2x32(0u, 1234u, 1u, 3u, a1, b1);
    k1a = a0; k1b = a1; }
#endif

  float nrm = normal_from_bits(rand_bits(k1a, k1b, i, (INP * OUTD) / 2));
  int r = i >> 7, c = i & 127;   // w[r][c]: r = k (input dim), c = n (output dim)
  float wv = w[i];
  float wq = rintf(fminf(fmaxf(wv * 128.f, -127.f), 127.f)) * 0.0078125f;
  wt[c * WT_STRIDE + r] = (__bf16)(wq + (nrm * wmax) * 0.1f);
}

// ---------------- main ----------------
// R7: LANE-CONTIGUOUS global reads (1 KB per instruction, one request per
// 128-B line — the float4-copy pattern) + per-wave LDS transpose (stride 132
// spreads banks) to recover the MFMA A-fragment layout. R1-R6 all read x
// with 16-line/request half-line-covered gathers and all pinned at 2.2 TB/s;
// stores proven irrelevant (R3 scattered == R5 coalesced == R6 nontemporal).
__device__ __forceinline__ void load_tile_contig(floatx4 v[8], const float* __restrict__ x,
                                                 long tile, int lane) {
  const float* p = x + ((size_t)tile << 11) + lane * 4;   // tile*2048 floats
  #pragma unroll
  for (int k = 0; k < 8; ++k) v[k] = *(const floatx4*)(p + k * 256);
}

// deposit: instr k holds rows {2k, 2k+1}; lane i -> row 2k+(i>>5), col (i&31)*4
__device__ __forceinline__ void stage_tile(const floatx4 v[8], float* __restrict__ myX,
                                           int lane) {
  const int r0 = lane >> 5;
  const int c  = (lane & 31) * 4;
  #pragma unroll
  for (int k = 0; k < 8; ++k)
    *(floatx4*)&myX[(2 * k + r0) * XT_STRIDE + c] = v[k];
}

__device__ __forceinline__ bf16x8 quant_pair(floatx4 v0, floatx4 v1, float s1, float r1) {
  bf16x8 a;
  #pragma unroll
  for (int i = 0; i < 4; ++i) {
    a[i]     = (__bf16)(rintf(fminf(fmaxf(v0[i] * s1, -127.f), 127.f)) * r1);
    a[i + 4] = (__bf16)(rintf(fminf(fmaxf(v1[i] * s1, -127.f), 127.f)) * r1);
  }
  return a;
}

__device__ __forceinline__ void compute_tile(
    const float* __restrict__ myX, const __bf16* sW, const float* sBias,
    float* __restrict__ out, long tile, int n16, int quad,
    float s1, float r1, float s2, float r2) {
  floatx4 acc[8];
  #pragma unroll
  for (int ct = 0; ct < 8; ++ct) acc[ct] = (floatx4)0.0f;

  #pragma unroll
  for (int kc = 0; kc < 4; ++kc) {
    const float* fr = &myX[n16 * XT_STRIDE + kc * 32 + quad * 8];
    floatx4 f0 = *(const floatx4*)fr;          // ds_read_b128
    floatx4 f1 = *(const floatx4*)(fr + 4);    // ds_read_b128
    bf16x8 a = quant_pair(f0, f1, s1, r1);
    const int kOff = kc * 32 + quad * 8;
    #pragma unroll
    for (int ct = 0; ct < 8; ++ct) {
      bf16x8 wfrag = *(const bf16x8*)&sW[(ct * 16 + n16) * WT_STRIDE + kOff];
      // swapped operands: D[i=outcol][j=batchrow] (transposed C/D)
      acc[ct] = __builtin_amdgcn_mfma_f32_16x16x32_bf16(wfrag, a, acc[ct], 0, 0, 0);
    }
  }

  // epilogue: lane&15 = batch row, quad*4+r = out col -> coalesced dwordx4
  float* orow = out + ((size_t)(tile * 16 + n16) << 7);
  #pragma unroll
  for (int ct = 0; ct < 8; ++ct) {
    const int colBase = ct * 16 + quad * 4;
    floatx4 o;
    #pragma unroll
    for (int r = 0; r < 4; ++r) {
      float h = acc[ct][r] + sBias[colBase + r];
      float t = fminf(fmaxf(h * s2, -127.0f), 127.0f);
      o[r] = rintf(t) * r2;
    }
    *(floatx4*)(orow + colBase) = o;
  }
}

__global__ __launch_bounds__(256) void linlayer_main(
    const float* __restrict__ x, const __bf16* __restrict__ wt,
    const float* __restrict__ biasEff, const float* __restrict__ a1p,
    const float* __restrict__ a2p, float* __restrict__ out, int nTiles) {
  __shared__ __attribute__((aligned(16))) __bf16 sW[OUTD * WT_STRIDE];
  __shared__ __attribute__((aligned(16))) float sX[4][16 * XT_STRIDE];
  __shared__ float sBias[OUTD];

  const int tid  = threadIdx.x;
  const int wave = tid >> 6;
  const int lane = tid & 63;
  const int n16  = lane & 15;
  const int quad = lane >> 4;

  const int nWaves = gridDim.x * 4;
  const int waveId = blockIdx.x * 4 + wave;
  const long last  = nTiles - 1;

  // prefetch tile 0 BEFORE the W-stage barrier (registers only, no LDS dep)
  floatx4 bufA[8], bufB[8];
  long t = waveId;
  load_tile_contig(bufA, x, (t <= last) ? t : last, lane);

  // stage W' (34816 B) into LDS — once per block
  {
    const uint4* src = (const uint4*)wt;
    uint4* dst = (uint4*)sW;
    for (int i = tid; i < (OUTD * WT_STRIDE * 2) / 16; i += 256) dst[i] = src[i];
  }
  if (tid < OUTD) sBias[tid] = biasEff[tid];

  const float a1 = a1p[0], a2 = a2p[0];
  const float s1 = 128.0f / a1, r1 = a1 * 0.0078125f;  // 32, 1/32 (exact pow2)
  const float s2 = 128.0f / a2, r2 = a2 * 0.0078125f;  // 8, 0.125

  __syncthreads();   // the only barrier

  float* myX = sX[wave];

  while (t <= last) {
    long tn = t + nWaves;
    load_tile_contig(bufB, x, (tn <= last) ? tn : last, lane);  // in flight during tile t
    stage_tile(bufA, myX, lane);        // waits vmcnt for bufA only (issued last iter)
    compute_tile(myX, sW, sBias, out, t, n16, quad, s1, r1, s2, r2);
    t = tn;
    if (t > last) break;

    tn = t + nWaves;
    load_tile_contig(bufA, x, (tn <= last) ? tn : last, lane);
    stage_tile(bufB, myX, lane);
    compute_tile(myX, sW, sBias, out, t, n16, quad, s1, r1, s2, r2);
    t = tn;
  }
}

extern "C" void kernel_launch(void* const* d_in, const int* in_sizes, int n_in,
                              void* d_out, int out_size, void* d_ws, size_t ws_size,
                              hipStream_t stream) {
  const float* x    = (const float*)d_in[0];
  const float* w    = (const float*)d_in[1];
  const float* bias = (const float*)d_in[2];
  const float* a1   = (const float*)d_in[3];
  const float* a2   = (const float*)d_in[4];
  float* out = (float*)d_out;

  __bf16* wt     = (__bf16*)d_ws;                                   // 34816 B
  float* biasEff = (float*)((char*)d_ws + OUTD * WT_STRIDE * 2);    // +512 B
  float* scalars = (float*)((char*)d_ws + OUTD * WT_STRIDE * 2 + 512);

  const int rows   = in_sizes[0] / INP;   // 262144
  const int nTiles = rows / 16;           // 16384 16-row wave-tiles
  const int grid   = 512;                 // ~69 KB LDS -> 2 blocks/CU, 8 tiles/wave

  setup_reduce<<<1, 256, 0, stream>>>(w, bias, biasEff, scalars);
  setup_noise<<<64, 256, 0, stream>>>(w, wt, scalars);
  linlayer_main<<<grid, 256, 0, stream>>>(x, wt, biasEff, a1, a2, out, nTiles);
}